// Round 10
// baseline (266.087 us; speedup 1.0000x reference)
//
#include <hip/hip_runtime.h>
#include <hip/hip_bf16.h>

#define NPTS 150
#define KP   160          // EXACT MFMA k-range 0..159 (was 168; cols 160-167 never read)
#define NPAR 193
#define OSTR 388

// bf16 transposed activation buffers (element offsets into sT), 48 rows x 160.
// ONE shared ones-row (ONESR) replaces the three per-buffer ones rows; the
// MFMA B-pointer selects it for row bcols-1.
#define H1T   0           // [10][160] h1^T
#define H2T   1600        // [10][160] h2^T
#define XT    3200        // [4][160]  x^T
#define ONESR 3840        // [1][160]  shared ones row
#define DZ2T  4000        // [10][160]
#define DZ1T  5600        // [10][160]
#define DLT   7200        // [3][160]
#define TTOT  7680        // 48 rows x 160 = 15360 B

typedef __attribute__((ext_vector_type(8))) short short8;
typedef __attribute__((ext_vector_type(4))) float f32x4;
typedef __attribute__((ext_vector_type(2))) float f32x2;

// EMPIRICAL LAWS (rounds 1-9):
//  - VGPR=84 <-> ~3.4 blocks/CU (occ 31.6%); VGPR>=88 <-> ~1.9 blocks/CU.
//  - Residency matches a 64KB LDS carve: 64K/17.9K=3.57 (r1-r9), 64K/35.3K=
//    1.81 (r5 measured 1.79). THIS round: shrink block LDS to 16192B -> 4
//    blocks/CU if the carve theory holds.
//  - Wins come from shortening the pre-B1 serial latency chain (r9: x^T from
//    registers, -20us), NOT from bulk VALU cuts (r3 null).
// Round-10: KP=160 + shared ones-row (LDS 17632->16192), LRS select chain
// (kills dependent scalar load), fv hoist (kills t0 tail HBM load).
__global__ __launch_bounds__(192)
__attribute__((amdgpu_waves_per_eu(2, 4)))
void mlp_kernelA(
    const float* __restrict__ W1, const float* __restrict__ b1,
    const float* __restrict__ W2, const float* __restrict__ b2,
    const float* __restrict__ W3, const float* __restrict__ b3,
    const float* __restrict__ G1, const float* __restrict__ G2,
    const float* __restrict__ G3, const float* __restrict__ G4,
    const float* __restrict__ G5, const float* __restrict__ G6,
    const float* __restrict__ dx, const float* __restrict__ fv,
    const int* __restrict__ dy, const int* __restrict__ stepsz,
    float* __restrict__ out, float* __restrict__ slots, int storeMode)
{
    const int m    = blockIdx.x;
    const int t    = threadIdx.x;
    const int lane = t & 63;
    const int w    = t >> 6;

    __shared__ alignas(16) __hip_bfloat16 sT[TTOT];
    __shared__ alignas(16) float sP[200];
    __shared__ float red[8];

    // ---- branchless lr (was __constant__ table: a dependent scalar load) ----
    const int ss = stepsz[m];
    const float lr = (ss==0)?1e-3f:(ss==1)?1e-2f:(ss==2)?0.05f:
                     (ss==3)?0.1f :(ss==4)?0.5f :1.0f;
    const float fvv = fv[m];     // uniform -> s_load; hoisted off t0's tail

    // ---- SGD update: each thread computes param index t (t=0 also does 192) ----
    float pv;
    if      (t < 40)  pv = W1[m*40 + t]        - lr * G1[m*40 + t];
    else if (t < 50)  pv = b1[m*10 + (t-40)]   - lr * G2[m*10 + (t-40)];
    else if (t < 150) pv = W2[m*100 + (t-50)]  - lr * G3[m*100 + (t-50)];
    else if (t < 160) pv = b2[m*10 + (t-150)]  - lr * G4[m*10 + (t-150)];
    else if (t < 190) pv = W3[m*30 + (t-160)]  - lr * G5[m*30 + (t-160)];
    else              pv = b3[m*3 + (t-190)]   - lr * G6[m*3 + (t-190)];
    sP[t] = pv;
    out[(size_t)m*OSTR + t] = fminf(fmaxf(pv, -10000.f), 10000.f);
    if (t == 0) {
        float p192 = b3[m*3 + 2] - lr * G6[m*3 + 2];
        sP[192] = p192;
        out[(size_t)m*OSTR + 192] = fminf(fmaxf(p192, -10000.f), 10000.f);
    }

    // ---- per-thread data point (early: HBM latency overlaps staging) ----
    const bool act = (t < NPTS);
    const int  nc  = act ? t : 0;
    const f32x4 xv = ((const f32x4*)dx)[nc];
    const int   yv = dy[nc];

    // ---- pad zero: cols 150..159 of ALL 48 rows (A-side pads must be 0.0;
    //      B-side pads finite — uninit LDS as bf16 can be NaN and 0*NaN=NaN).
    //      Row base = 320B (16-aligned); col 150 -> +300 (4-al), 152 -> +304
    //      (16-al). 96 jobs. ----
    if (t < 96) {
        int r = t >> 1;
        __hip_bfloat16* rowp = sT + r*KP;
        if (t & 1) {
            *(float*)(rowp + 150) = 0.f;          // cols 150,151
        } else {
            f32x4 z = {0.f, 0.f, 0.f, 0.f};
            *(f32x4*)(rowp + 152) = z;            // cols 152..159
        }
    }
    // ---- shared ones row + x^T from registers: x^T[f][t] = xv[f] ----
    if (act) {
        sT[ONESR + t] = __float2bfloat16(1.0f);
        sT[XT + 0*KP + t] = __float2bfloat16(xv.x);
        sT[XT + 1*KP + t] = __float2bfloat16(xv.y);
        sT[XT + 2*KP + t] = __float2bfloat16(xv.z);
        sT[XT + 3*KP + t] = __float2bfloat16(xv.w);
    }

    __syncthreads();   // B1: sP + sT staging complete

    // ---- per-wave preload via aligned f32x2 LDS reads (all offsets even) ----
    float w2[10][10], bb2[10], w3[3][10], bb3[3], bb1[10];
    {
        const f32x2* p2 = (const f32x2*)sP;
        #pragma unroll
        for (int g = 0; g < 10; g++) {
            #pragma unroll
            for (int p = 0; p < 5; p++) {
                f32x2 v = p2[(50 + g*10)/2 + p];
                w2[g][2*p] = v.x; w2[g][2*p+1] = v.y;
            }
        }
        #pragma unroll
        for (int p = 0; p < 5; p++) {
            f32x2 v = p2[75 + p];                 // sP[150..159]
            bb2[2*p] = v.x; bb2[2*p+1] = v.y;
        }
        #pragma unroll
        for (int o = 0; o < 3; o++) {
            #pragma unroll
            for (int p = 0; p < 5; p++) {
                f32x2 v = p2[(160 + o*10)/2 + p];
                w3[o][2*p] = v.x; w3[o][2*p+1] = v.y;
            }
        }
        {
            f32x2 v = p2[95];                     // sP[190],sP[191]
            bb3[0] = v.x; bb3[1] = v.y; bb3[2] = sP[192];
        }
        #pragma unroll
        for (int p = 0; p < 5; p++) {
            f32x2 v = p2[20 + p];                 // sP[40..49]
            bb1[2*p] = v.x; bb1[2*p+1] = v.y;
        }
    }
    const f32x4* sP4 = (const f32x4*)sP;   // W1 row j at sP4[j]

    // ================= fused forward + backward-dz: ONE point per thread =====
    float lossacc = 0.f, ssacc = 0.f;
    {
        const int n = t;

        float h1v[10];
        #pragma unroll
        for (int j = 0; j < 10; j++) {
            f32x4 wv = sP4[j];
            float z = bb1[j] + xv.x*wv.x + xv.y*wv.y + xv.z*wv.z + xv.w*wv.w;
            h1v[j] = fmaxf(z, 0.f);
        }
        float h2v[10];
        #pragma unroll
        for (int g = 0; g < 10; g++) {
            float z = bb2[g];
            #pragma unroll
            for (int h = 0; h < 10; h++) z += h1v[h] * w2[g][h];
            h2v[g] = fmaxf(z, 0.f);
        }
        float lg[3];
        #pragma unroll
        for (int o = 0; o < 3; o++) {
            float z = bb3[o];
            #pragma unroll
            for (int g = 0; g < 10; g++) z += h2v[g] * w3[o][g];
            lg[o] = z;
        }
        float mx = fmaxf(lg[0], fmaxf(lg[1], lg[2]));
        float e0 = __expf(lg[0]-mx), e1 = __expf(lg[1]-mx), e2 = __expf(lg[2]-mx);
        float s   = e0 + e1 + e2;
        float inv = 1.f / s;
        float lse = mx + __logf(s);
        float ly  = (yv == 0) ? lg[0] : ((yv == 1) ? lg[1] : lg[2]);
        lossacc = act ? (lse - ly) : 0.f;

        float dl[3];
        dl[0] = (e0*inv - ((yv==0)?1.f:0.f)) * (1.f/150.f);
        dl[1] = (e1*inv - ((yv==1)?1.f:0.f)) * (1.f/150.f);
        dl[2] = (e2*inv - ((yv==2)?1.f:0.f)) * (1.f/150.f);

        float dz2v[10];
        #pragma unroll
        for (int g = 0; g < 10; g++) {
            float d = dl[0]*w3[0][g] + dl[1]*w3[1][g] + dl[2]*w3[2][g];
            dz2v[g] = (h2v[g] > 0.f) ? d : 0.f;
        }
        float dz1v[10];
        #pragma unroll
        for (int h = 0; h < 10; h++) {
            float d = 0.f;
            #pragma unroll
            for (int g = 0; g < 10; g++) d += dz2v[g] * w2[g][h];
            dz1v[h] = (h1v[h] > 0.f) ? d : 0.f;
        }

        if (act) {
            #pragma unroll
            for (int j = 0; j < 10; j++) sT[H1T  + j*KP + n] = __float2bfloat16(h1v[j]);
            #pragma unroll
            for (int g = 0; g < 10; g++) sT[H2T  + g*KP + n] = __float2bfloat16(h2v[g]);
            #pragma unroll
            for (int o = 0; o < 3;  o++) sT[DLT  + o*KP + n] = __float2bfloat16(dl[o]);
            #pragma unroll
            for (int g = 0; g < 10; g++) sT[DZ2T + g*KP + n] = __float2bfloat16(dz2v[g]);
            #pragma unroll
            for (int h = 0; h < 10; h++) sT[DZ1T + h*KP + n] = __float2bfloat16(dz1v[h]);
        }
    }
    __syncthreads();   // B2

    // ================= weight-grad GEMMs via MFMA: one tile per wave =========
    {
        const short* sTs = reinterpret_cast<const short*>(sT);
        const int mrow = lane & 15, q = lane >> 4;

        int abase, arows, bbase, bcols, woff, nW, boff;
        if      (w == 0) { abase=DZ2T; arows=10; bbase=H1T; bcols=11; woff=50;  nW=10; boff=150; }
        else if (w == 1) { abase=DZ1T; arows=10; bbase=XT;  bcols=5;  woff=0;   nW=4;  boff=40;  }
        else             { abase=DLT;  arows=3;  bbase=H2T; bcols=11; woff=160; nW=10; boff=190; }

        int ar = (mrow < arows) ? mrow : 0;
        int br = (mrow < bcols) ? mrow : 0;
        // row bcols-1 of the B operand is the SHARED ones row
        const short* aptr = sTs + abase + ar*KP;
        const short* bptr = sTs + ((br == bcols-1) ? ONESR : bbase + br*KP);
        f32x4 acc = {0.f, 0.f, 0.f, 0.f};
        #pragma unroll
        for (int kk = 0; kk < 5; kk++) {
            int k0 = kk*32 + q*8;
            short8 a = *(const short8*)(aptr + k0);
            short8 b = *(const short8*)(bptr + k0);
            acc = __builtin_amdgcn_mfma_f32_16x16x32_bf16(a, b, acc, 0, 0, 0);
        }
        #pragma unroll
        for (int r = 0; r < 4; r++) {
            int row = q*4 + r;
            if (row < arows && mrow < bcols) {
                float v = acc[r];
                int off = (mrow < nW) ? (woff + row*nW + mrow) : (boff + row);
                out[(size_t)m*OSTR + NPAR + off] = v;   // raw grad; kernel C scales
                ssacc += v*v;
            }
        }
    }

    // ---- reductions: loss (across all 3 waves), sumsq (per-wave tiles) ----
    #pragma unroll
    for (int off = 32; off > 0; off >>= 1) {
        lossacc += __shfl_down(lossacc, off, 64);
        ssacc   += __shfl_down(ssacc,   off, 64);
    }
    if (lane == 0) { red[w] = lossacc; red[4 + w] = ssacc; }
    __syncthreads();   // B3
    if (t == 0) {
        float blockss = red[4] + red[5] + red[6];
        if (storeMode) slots[1 + m] = blockss;
        else           atomicAdd(&slots[1 + (m & 1023)], blockss);
        float loss = (red[0] + red[1] + red[2]) * (1.f/150.f);
        out[(size_t)m*OSTR + 386] = loss;
        float imp = fvv - loss;
        imp = fminf(fmaxf(imp, -10000.f), 10000.f);
        out[(size_t)m*OSTR + 387] = imp;
    }
}

// 64-block reduction -> raw total into slots[0] (aligned f32x4 loads; slot 0
// is pre-zeroed in both modes so including it is identity).
__global__ __launch_bounds__(256) void mlp_kernelB(float* __restrict__ slots, int count)
{
    int idx = blockIdx.x * 256 + threadIdx.x;
    int stride = gridDim.x * 256;
    int n4 = (count + 1) >> 2;
    const f32x4* s4 = (const f32x4*)slots;
    float v = 0.f;
    for (int i = idx; i < n4; i += stride) {
        f32x4 q = s4[i];
        v += q.x + q.y + q.z + q.w;
    }
    if (idx == 0)
        for (int i = 4*n4; i <= count; i++) v += slots[i];
    #pragma unroll
    for (int off = 32; off > 0; off >>= 1) v += __shfl_down(v, off, 64);
    __shared__ float red[4];
    int t = threadIdx.x;
    if ((t & 63) == 0) red[t >> 6] = v;
    __syncthreads();
    if (t == 0) {
        float total = red[0] + red[1] + red[2] + red[3];
        atomicAdd(&slots[0], total);
    }
}

// One block per MLP, coalesced RMW over the 193 grad slots.
__global__ __launch_bounds__(192) void mlp_kernelC(float* __restrict__ out,
                                                   const float* __restrict__ slots)
{
    float total = slots[0];
    float coef = fminf(1.f, 10.f / (sqrtf(total) + 1e-6f));
    size_t base = (size_t)blockIdx.x * OSTR + NPAR;
    int t = threadIdx.x;
    out[base + t] *= coef;
    if (t == 0) out[base + 192] *= coef;
}

extern "C" void kernel_launch(void* const* d_in, const int* in_sizes, int n_in,
                              void* d_out, int out_size, void* d_ws, size_t ws_size,
                              hipStream_t stream) {
    const float* W1 = (const float*)d_in[0];
    const float* b1 = (const float*)d_in[1];
    const float* W2 = (const float*)d_in[2];
    const float* b2 = (const float*)d_in[3];
    const float* W3 = (const float*)d_in[4];
    const float* b3 = (const float*)d_in[5];
    const float* G1 = (const float*)d_in[6];
    const float* G2 = (const float*)d_in[7];
    const float* G3 = (const float*)d_in[8];
    const float* G4 = (const float*)d_in[9];
    const float* G5 = (const float*)d_in[10];
    const float* G6 = (const float*)d_in[11];
    const float* dx = (const float*)d_in[12];
    const float* fv = (const float*)d_in[13];
    const int*   dy = (const int*)d_in[14];
    const int*   st = (const int*)d_in[15];
    float* out   = (float*)d_out;
    float* slots = (float*)d_ws;

    int Bn = in_sizes[0] / 40;
    int storeMode = (ws_size >= (size_t)(Bn + 2) * sizeof(float)) ? 1 : 0;

    if (storeMode) hipMemsetAsync(d_ws, 0, 4, stream);       // just slots[0]
    else           hipMemsetAsync(d_ws, 0, 4100, stream);    // slots[0..1024]
    mlp_kernelA<<<Bn, 192, 0, stream>>>(W1,b1,W2,b2,W3,b3,
                                        G1,G2,G3,G4,G5,G6,
                                        dx,fv,dy,st,out,slots,storeMode);
    mlp_kernelB<<<64, 256, 0, stream>>>(slots, storeMode ? Bn : 1024);
    mlp_kernelC<<<Bn, 192, 0, stream>>>(out, slots);
}

// Round 11
// 265.153 us; speedup vs baseline: 1.0035x; 1.0035x over previous
//
#include <hip/hip_runtime.h>
#include <hip/hip_bf16.h>

#define NPTS 150
#define KP   160          // EXACT MFMA k-range 0..159
#define NPAR 193
#define OSTR 388

// bf16 transposed activation buffers (element offsets into sT), 48 rows x 160.
#define H1T   0           // [10][160] h1^T
#define H2T   1600        // [10][160] h2^T
#define XT    3200        // [4][160]  x^T
#define ONESR 3840        // [1][160]  shared ones row
#define DZ2T  4000        // [10][160]
#define DZ1T  5600        // [10][160]
#define DLT   7200        // [3][160]
#define TTOT  7680        // 48 rows x 160 = 15360 B

typedef __attribute__((ext_vector_type(8))) short short8;
typedef __attribute__((ext_vector_type(4))) float f32x4;
typedef __attribute__((ext_vector_type(2))) float f32x2;

// EMPIRICAL LAWS (rounds 1-10):
//  - Dynamic residency ~3.37 blocks/CU is an attractor: not LDS (r10 refuted
//    the 64K-carve), not static VGPR caps. Restructures (r2/r4/r5/r7) all
//    broke it; the r1 skeleton holds it.
//  - Wins come from shortening the per-block critical path at constant
//    skeleton (r8 -6us, r9 -20us). VALUBusy has climbed 58->66% doing so.
// Round-11: the regime changed -> re-run r3's packed-math experiment (f32x2
// v_pk_fma for h2/lg/dz2/dz1, W2/W3 rows read as ds_read_b64 straight from
// sP). In r3 (latency-bound, 48% VALU) it was null; at 66% VALU it should
// pay ~15% issue reduction. VGPR was 84 with this body in r3.
__global__ __launch_bounds__(192)
__attribute__((amdgpu_waves_per_eu(2, 4)))
void mlp_kernelA(
    const float* __restrict__ W1, const float* __restrict__ b1,
    const float* __restrict__ W2, const float* __restrict__ b2,
    const float* __restrict__ W3, const float* __restrict__ b3,
    const float* __restrict__ G1, const float* __restrict__ G2,
    const float* __restrict__ G3, const float* __restrict__ G4,
    const float* __restrict__ G5, const float* __restrict__ G6,
    const float* __restrict__ dx, const float* __restrict__ fv,
    const int* __restrict__ dy, const int* __restrict__ stepsz,
    float* __restrict__ out, float* __restrict__ slots, int storeMode)
{
    const int m    = blockIdx.x;
    const int t    = threadIdx.x;
    const int lane = t & 63;
    const int w    = t >> 6;

    __shared__ alignas(16) __hip_bfloat16 sT[TTOT];
    __shared__ alignas(16) float sP[200];
    __shared__ float red[8];

    // ---- branchless lr + hoisted fv (both uniform -> scalar ops) ----
    const int ss = stepsz[m];
    const float lr = (ss==0)?1e-3f:(ss==1)?1e-2f:(ss==2)?0.05f:
                     (ss==3)?0.1f :(ss==4)?0.5f :1.0f;
    const float fvv = fv[m];

    // ---- SGD update: each thread computes param index t (t=0 also does 192) ----
    float pv;
    if      (t < 40)  pv = W1[m*40 + t]        - lr * G1[m*40 + t];
    else if (t < 50)  pv = b1[m*10 + (t-40)]   - lr * G2[m*10 + (t-40)];
    else if (t < 150) pv = W2[m*100 + (t-50)]  - lr * G3[m*100 + (t-50)];
    else if (t < 160) pv = b2[m*10 + (t-150)]  - lr * G4[m*10 + (t-150)];
    else if (t < 190) pv = W3[m*30 + (t-160)]  - lr * G5[m*30 + (t-160)];
    else              pv = b3[m*3 + (t-190)]   - lr * G6[m*3 + (t-190)];
    sP[t] = pv;
    out[(size_t)m*OSTR + t] = fminf(fmaxf(pv, -10000.f), 10000.f);
    if (t == 0) {
        float p192 = b3[m*3 + 2] - lr * G6[m*3 + 2];
        sP[192] = p192;
        out[(size_t)m*OSTR + 192] = fminf(fmaxf(p192, -10000.f), 10000.f);
    }

    // ---- per-thread data point (early: HBM latency overlaps staging) ----
    const bool act = (t < NPTS);
    const int  nc  = act ? t : 0;
    const f32x4 xv = ((const f32x4*)dx)[nc];
    const int   yv = dy[nc];

    // ---- pad zero: cols 150..159 of all 48 rows ----
    if (t < 96) {
        int r = t >> 1;
        __hip_bfloat16* rowp = sT + r*KP;
        if (t & 1) {
            *(float*)(rowp + 150) = 0.f;          // cols 150,151
        } else {
            f32x4 z = {0.f, 0.f, 0.f, 0.f};
            *(f32x4*)(rowp + 152) = z;            // cols 152..159
        }
    }
    // ---- shared ones row + x^T from registers ----
    if (act) {
        sT[ONESR + t] = __float2bfloat16(1.0f);
        sT[XT + 0*KP + t] = __float2bfloat16(xv.x);
        sT[XT + 1*KP + t] = __float2bfloat16(xv.y);
        sT[XT + 2*KP + t] = __float2bfloat16(xv.z);
        sT[XT + 3*KP + t] = __float2bfloat16(xv.w);
    }

    __syncthreads();   // B1: sP + sT staging complete

    const f32x4* sP4 = (const f32x4*)sP;   // W1 row j at sP4[j]
    const f32x2* sP2 = (const f32x2*)sP;   // W2 row g at sP2+25+g*5; W3 at +80+o*5
    const f32x2  x01 = {xv.x, xv.y}, x23 = {xv.z, xv.w};

    // ================= fused forward + backward-dz (packed f32x2 math) ======
    float lossacc = 0.f, ssacc = 0.f;
    {
        const int n = t;

        float h1v[10];
        #pragma unroll
        for (int j = 0; j < 10; j++) {
            f32x2 a = x01 * sP2[2*j] + x23 * sP2[2*j+1];
            float z = sP[40+j] + a.x + a.y;
            h1v[j] = fmaxf(z, 0.f);
        }
        f32x2 hh[5];
        #pragma unroll
        for (int p = 0; p < 5; p++) hh[p] = (f32x2){h1v[2*p], h1v[2*p+1]};

        float h2v[10];
        #pragma unroll
        for (int g = 0; g < 10; g++) {
            const f32x2* wr = sP2 + 25 + g*5;        // W2 row g (row-major)
            f32x2 a = hh[0]*wr[0] + hh[1]*wr[1];
            a += hh[2]*wr[2] + hh[3]*wr[3];
            a += hh[4]*wr[4];
            float z = sP[150+g] + a.x + a.y;
            h2v[g] = fmaxf(z, 0.f);
        }
        f32x2 h2h[5];
        #pragma unroll
        for (int p = 0; p < 5; p++) h2h[p] = (f32x2){h2v[2*p], h2v[2*p+1]};

        float lg[3];
        #pragma unroll
        for (int o = 0; o < 3; o++) {
            const f32x2* wr = sP2 + 80 + o*5;        // W3 row o
            f32x2 a = h2h[0]*wr[0] + h2h[1]*wr[1];
            a += h2h[2]*wr[2] + h2h[3]*wr[3];
            a += h2h[4]*wr[4];
            lg[o] = sP[190+o] + a.x + a.y;
        }

        float mx = fmaxf(lg[0], fmaxf(lg[1], lg[2]));
        float e0 = __expf(lg[0]-mx), e1 = __expf(lg[1]-mx), e2 = __expf(lg[2]-mx);
        float s   = e0 + e1 + e2;
        float inv = 1.f / s;
        float lse = mx + __logf(s);
        float ly  = (yv == 0) ? lg[0] : ((yv == 1) ? lg[1] : lg[2]);
        lossacc = act ? (lse - ly) : 0.f;

        float dl[3];
        dl[0] = (e0*inv - ((yv==0)?1.f:0.f)) * (1.f/150.f);
        dl[1] = (e1*inv - ((yv==1)?1.f:0.f)) * (1.f/150.f);
        dl[2] = (e2*inv - ((yv==2)?1.f:0.f)) * (1.f/150.f);

        // dz2[g] = sum_o dl[o]*W3[o][g], packed over g-pairs (row-major reads)
        f32x2 dz2a[5];
        #pragma unroll
        for (int p = 0; p < 5; p++) dz2a[p] = (f32x2){0.f, 0.f};
        #pragma unroll
        for (int o = 0; o < 3; o++) {
            f32x2 d = {dl[o], dl[o]};
            const f32x2* wr = sP2 + 80 + o*5;
            #pragma unroll
            for (int p = 0; p < 5; p++) dz2a[p] += d * wr[p];
        }
        float dz2v[10];
        #pragma unroll
        for (int g = 0; g < 10; g++) {
            float d = (g & 1) ? dz2a[g>>1].y : dz2a[g>>1].x;
            dz2v[g] = (h2v[g] > 0.f) ? d : 0.f;
        }

        // dz1[h] = sum_g dz2[g]*W2[g][h], g-outer so reads stay row-major
        f32x2 dz1a[5];
        #pragma unroll
        for (int p = 0; p < 5; p++) dz1a[p] = (f32x2){0.f, 0.f};
        #pragma unroll
        for (int g = 0; g < 10; g++) {
            f32x2 d = {dz2v[g], dz2v[g]};
            const f32x2* wr = sP2 + 25 + g*5;
            #pragma unroll
            for (int p = 0; p < 5; p++) dz1a[p] += d * wr[p];
        }
        float dz1v[10];
        #pragma unroll
        for (int h = 0; h < 10; h++) {
            float d = (h & 1) ? dz1a[h>>1].y : dz1a[h>>1].x;
            dz1v[h] = (h1v[h] > 0.f) ? d : 0.f;
        }

        if (act) {
            #pragma unroll
            for (int j = 0; j < 10; j++) sT[H1T  + j*KP + n] = __float2bfloat16(h1v[j]);
            #pragma unroll
            for (int g = 0; g < 10; g++) sT[H2T  + g*KP + n] = __float2bfloat16(h2v[g]);
            #pragma unroll
            for (int o = 0; o < 3;  o++) sT[DLT  + o*KP + n] = __float2bfloat16(dl[o]);
            #pragma unroll
            for (int g = 0; g < 10; g++) sT[DZ2T + g*KP + n] = __float2bfloat16(dz2v[g]);
            #pragma unroll
            for (int h = 0; h < 10; h++) sT[DZ1T + h*KP + n] = __float2bfloat16(dz1v[h]);
        }
    }
    __syncthreads();   // B2

    // ================= weight-grad GEMMs via MFMA: one tile per wave =========
    {
        const short* sTs = reinterpret_cast<const short*>(sT);
        const int mrow = lane & 15, q = lane >> 4;

        int abase, arows, bbase, bcols, woff, nW, boff;
        if      (w == 0) { abase=DZ2T; arows=10; bbase=H1T; bcols=11; woff=50;  nW=10; boff=150; }
        else if (w == 1) { abase=DZ1T; arows=10; bbase=XT;  bcols=5;  woff=0;   nW=4;  boff=40;  }
        else             { abase=DLT;  arows=3;  bbase=H2T; bcols=11; woff=160; nW=10; boff=190; }

        int ar = (mrow < arows) ? mrow : 0;
        int br = (mrow < bcols) ? mrow : 0;
        const short* aptr = sTs + abase + ar*KP;
        const short* bptr = sTs + ((br == bcols-1) ? ONESR : bbase + br*KP);
        f32x4 acc = {0.f, 0.f, 0.f, 0.f};
        #pragma unroll
        for (int kk = 0; kk < 5; kk++) {
            int k0 = kk*32 + q*8;
            short8 a = *(const short8*)(aptr + k0);
            short8 b = *(const short8*)(bptr + k0);
            acc = __builtin_amdgcn_mfma_f32_16x16x32_bf16(a, b, acc, 0, 0, 0);
        }
        #pragma unroll
        for (int r = 0; r < 4; r++) {
            int row = q*4 + r;
            if (row < arows && mrow < bcols) {
                float v = acc[r];
                int off = (mrow < nW) ? (woff + row*nW + mrow) : (boff + row);
                out[(size_t)m*OSTR + NPAR + off] = v;   // raw grad; kernel C scales
                ssacc += v*v;
            }
        }
    }

    // ---- reductions: loss (across all 3 waves), sumsq (per-wave tiles) ----
    #pragma unroll
    for (int off = 32; off > 0; off >>= 1) {
        lossacc += __shfl_down(lossacc, off, 64);
        ssacc   += __shfl_down(ssacc,   off, 64);
    }
    if (lane == 0) { red[w] = lossacc; red[4 + w] = ssacc; }
    __syncthreads();   // B3
    if (t == 0) {
        float blockss = red[4] + red[5] + red[6];
        if (storeMode) slots[1 + m] = blockss;
        else           atomicAdd(&slots[1 + (m & 1023)], blockss);
        float loss = (red[0] + red[1] + red[2]) * (1.f/150.f);
        out[(size_t)m*OSTR + 386] = loss;
        float imp = fvv - loss;
        imp = fminf(fmaxf(imp, -10000.f), 10000.f);
        out[(size_t)m*OSTR + 387] = imp;
    }
}

// 64-block reduction -> raw total into slots[0] (aligned f32x4 loads; slot 0
// is pre-zeroed in both modes so including it is identity).
__global__ __launch_bounds__(256) void mlp_kernelB(float* __restrict__ slots, int count)
{
    int idx = blockIdx.x * 256 + threadIdx.x;
    int stride = gridDim.x * 256;
    int n4 = (count + 1) >> 2;
    const f32x4* s4 = (const f32x4*)slots;
    float v = 0.f;
    for (int i = idx; i < n4; i += stride) {
        f32x4 q = s4[i];
        v += q.x + q.y + q.z + q.w;
    }
    if (idx == 0)
        for (int i = 4*n4; i <= count; i++) v += slots[i];
    #pragma unroll
    for (int off = 32; off > 0; off >>= 1) v += __shfl_down(v, off, 64);
    __shared__ float red[4];
    int t = threadIdx.x;
    if ((t & 63) == 0) red[t >> 6] = v;
    __syncthreads();
    if (t == 0) {
        float total = red[0] + red[1] + red[2] + red[3];
        atomicAdd(&slots[0], total);
    }
}

// One block per MLP, coalesced RMW over the 193 grad slots.
__global__ __launch_bounds__(192) void mlp_kernelC(float* __restrict__ out,
                                                   const float* __restrict__ slots)
{
    float total = slots[0];
    float coef = fminf(1.f, 10.f / (sqrtf(total) + 1e-6f));
    size_t base = (size_t)blockIdx.x * OSTR + NPAR;
    int t = threadIdx.x;
    out[base + t] *= coef;
    if (t == 0) out[base + 192] *= coef;
}

extern "C" void kernel_launch(void* const* d_in, const int* in_sizes, int n_in,
                              void* d_out, int out_size, void* d_ws, size_t ws_size,
                              hipStream_t stream) {
    const float* W1 = (const float*)d_in[0];
    const float* b1 = (const float*)d_in[1];
    const float* W2 = (const float*)d_in[2];
    const float* b2 = (const float*)d_in[3];
    const float* W3 = (const float*)d_in[4];
    const float* b3 = (const float*)d_in[5];
    const float* G1 = (const float*)d_in[6];
    const float* G2 = (const float*)d_in[7];
    const float* G3 = (const float*)d_in[8];
    const float* G4 = (const float*)d_in[9];
    const float* G5 = (const float*)d_in[10];
    const float* G6 = (const float*)d_in[11];
    const float* dx = (const float*)d_in[12];
    const float* fv = (const float*)d_in[13];
    const int*   dy = (const int*)d_in[14];
    const int*   st = (const int*)d_in[15];
    float* out   = (float*)d_out;
    float* slots = (float*)d_ws;

    int Bn = in_sizes[0] / 40;
    int storeMode = (ws_size >= (size_t)(Bn + 2) * sizeof(float)) ? 1 : 0;

    if (storeMode) hipMemsetAsync(d_ws, 0, 4, stream);       // just slots[0]
    else           hipMemsetAsync(d_ws, 0, 4100, stream);    // slots[0..1024]
    mlp_kernelA<<<Bn, 192, 0, stream>>>(W1,b1,W2,b2,W3,b3,
                                        G1,G2,G3,G4,G5,G6,
                                        dx,fv,dy,st,out,slots,storeMode);
    mlp_kernelB<<<64, 256, 0, stream>>>(slots, storeMode ? Bn : 1024);
    mlp_kernelC<<<Bn, 192, 0, stream>>>(out, slots);
}